// Round 6
// baseline (158.583 us; speedup 1.0000x reference)
//
#include <hip/hip_runtime.h>
#include <math.h>

#define IMG_H 512
#define IMG_W 512
#define NSLOT 64

typedef _Float16 f16x2 __attribute__((ext_vector_type(2)));
typedef _Float16 f16x4 __attribute__((ext_vector_type(4)));
typedef _Float16 f16x8 __attribute__((ext_vector_type(8)));
typedef float    f32x4 __attribute__((ext_vector_type(4)));
typedef unsigned int uint;

// Zero-padded 11-tap Gaussian (sigma=1.5), f16, normalized (1/sum = 0.26601173).
// Index domain: idx in [-18, 33] -> WPAD[idx + 18]. Nonzero only for idx in [0,10].
__device__ const _Float16 WPAD[52] = {
    (_Float16)0.f,(_Float16)0.f,(_Float16)0.f,(_Float16)0.f,(_Float16)0.f,(_Float16)0.f,
    (_Float16)0.f,(_Float16)0.f,(_Float16)0.f,(_Float16)0.f,(_Float16)0.f,(_Float16)0.f,
    (_Float16)0.f,(_Float16)0.f,(_Float16)0.f,(_Float16)0.f,(_Float16)0.f,(_Float16)0.f,   // idx -18..-1
    (_Float16)0.00102838f, (_Float16)0.00759876f, (_Float16)0.03600077f,
    (_Float16)0.10936065f, (_Float16)0.21300554f, (_Float16)0.26601173f,
    (_Float16)0.21300554f, (_Float16)0.10936065f, (_Float16)0.03600077f,
    (_Float16)0.00759876f, (_Float16)0.00102838f,                                          // idx 0..10
    (_Float16)0.f,(_Float16)0.f,(_Float16)0.f,(_Float16)0.f,(_Float16)0.f,(_Float16)0.f,
    (_Float16)0.f,(_Float16)0.f,(_Float16)0.f,(_Float16)0.f,(_Float16)0.f,(_Float16)0.f,
    (_Float16)0.f,(_Float16)0.f,(_Float16)0.f,(_Float16)0.f,(_Float16)0.f,(_Float16)0.f,
    (_Float16)0.f,(_Float16)0.f,(_Float16)0.f,(_Float16)0.f,(_Float16)0.f                  // idx 11..33
};

__device__ __forceinline__ f16x8 frag_from_tab(int base)
{
    f16x8 f;
    #pragma unroll
    for (int j = 0; j < 8; ++j) f[j] = WPAD[base + j];
    return f;
}

// Wave-private everything; no block barriers, no manual fences. Coalesced
// global loads (lane = row-octet x 16B slice) + LDS transpose to A-fragments.
// LDS = 32768 B exactly -> 5 blocks/CU.
__global__ __launch_bounds__(256, 5)
void ssim_main(const float* __restrict__ pred, const float* __restrict__ targ,
               float* __restrict__ partial, double* __restrict__ acc, int mode)
{
    // Staging: [wave][{s,d}][16 rows][64 B pitch] — reused across 3 row-tiles.
    // Pitch 64 B: 2-way bank aliasing on stg ops, accepted for the occupancy.
    __shared__ __align__(128) _Float16 stg[4][2][16][32];      // 8192 B
    // Transpose buffer: [wave][q][out_col][halo_row 0..47], 16-byte XOR swizzle.
    __shared__ __align__(128) _Float16 hT[4][4][16][48];       // 24576 B

    const int tid  = threadIdx.x;
    const int lane = tid & 63, wave = tid >> 6;
    const int ln   = lane & 15, lg = lane >> 4;
    const int l8   = lane >> 3, l7 = lane & 7;

    // XCD swizzle: contiguous chunk (= whole planes) per XCD.
    const int bid   = ((blockIdx.z * 16 + blockIdx.y) * 8) + blockIdx.x;
    const int chunk = (int)gridDim.z << 4;            // nwg/8
    const int nb    = (bid & 7) * chunk + (bid >> 3);
    const int img   = nb >> 7;                        // 128 blocks per plane
    const int rem   = nb & 127;
    const int ty    = rem >> 3, tx = rem & 7;

    const float* __restrict__ p = pred + (size_t)img * (IMG_H * IMG_W);
    const float* __restrict__ t = targ + (size_t)img * (IMG_H * IMG_W);

    // Wave strip: output rows ty*32..+31, cols tx*64 + wave*16 ..+15.
    const int gr0 = ty * 32 - 5;                      // halo row 0 (48 rows)
    const int wo  = tx * 64 + wave * 16 - 8;          // halo col 0 (32 cols)

    // Banded Gaussian fragments:
    // Bw (B-op, horiz):  B[k][n] = w[k-n-3] -> WPAD[15 + lg*8+j - ln]
    // A2w (A-op, vert):  A[m][k] = w[k-m]   -> WPAD[18 + lg*8+j - ln]
    const f16x8 Bw  = frag_from_tab(15 + lg * 8 - ln);
    const f16x8 A2w = frag_from_tab(18 + lg * 8 - ln);
    const f32x4 z = {0.f, 0.f, 0.f, 0.f};

    // ---- Phase 1: coalesced loads. Lane l -> row (i*8 + l>>3), 16 B at (l&7)*16.
    const int  cb    = wo * 4 + l7 * 16;              // column byte offset in row
    const int  cbc   = cb < 0 ? 0 : (cb > 2032 ? 2032 : cb);
    const bool colOK = (cb == cbc);

    uint2 sp[6], dp[6];
    #pragma unroll
    for (int i = 0; i < 6; ++i) {
        const int gr  = gr0 + i * 8 + l8;
        const int grc = gr < 0 ? 0 : (gr > IMG_H - 1 ? IMG_H - 1 : gr);
        const char* rp = (const char*)p + (size_t)grc * (IMG_W * 4) + cbc;
        const char* rq = (const char*)t + (size_t)grc * (IMG_W * 4) + cbc;
        float4 pv = *(const float4*)rp;
        float4 tv = *(const float4*)rq;
        const bool ok = ((unsigned)gr < (unsigned)IMG_H) && colOK;
        f16x2 s01 = {(_Float16)(pv.x + tv.x), (_Float16)(pv.y + tv.y)};
        f16x2 s23 = {(_Float16)(pv.z + tv.z), (_Float16)(pv.w + tv.w)};
        f16x2 d01 = {(_Float16)(pv.x - tv.x), (_Float16)(pv.y - tv.y)};
        f16x2 d23 = {(_Float16)(pv.z - tv.z), (_Float16)(pv.w - tv.w)};
        uint2 sv = {__builtin_bit_cast(uint, s01), __builtin_bit_cast(uint, s23)};
        uint2 dv = {__builtin_bit_cast(uint, d01), __builtin_bit_cast(uint, d23)};
        const uint2 zz = {0u, 0u};
        sp[i] = ok ? sv : zz;
        dp[i] = ok ? dv : zz;
    }

    // ---- Phase 2: per row-tile: stage s,d -> read A-frags -> MFMA -> hT.
    // All LDS via plain C++: compiler orders may-alias DS ops (per-wave DS is
    // in-order) and inserts minimal lgkmcnt — no manual fences.
    char* stgS = (char*)&stg[wave][0][0][0];
    char* stgD = (char*)&stg[wave][1][0][0];
    const int wB  = l8 * 64 + l7 * 8;      // write byte (row l8, 8B col slot)
    const int rB  = ln * 64 + lg * 16;     // frag read byte (row ln, 16B slice)
    const int swz = (ln & 4) << 2;         // hT 16-byte XOR swizzle (write & read)

    #pragma unroll
    for (int rt = 0; rt < 3; ++rt) {
        *(uint2*)(stgS + wB)       = sp[2 * rt];
        *(uint2*)(stgS + wB + 512) = sp[2 * rt + 1];   // rows 8..15 (+8*64 B)
        *(uint2*)(stgD + wB)       = dp[2 * rt];
        *(uint2*)(stgD + wB + 512) = dp[2 * rt + 1];
        f16x8 s8 = *(const f16x8*)(stgS + rB);
        f16x8 d8 = *(const f16x8*)(stgD + rB);
        f16x8 fq[4];
        fq[0] = s8; fq[1] = d8;
        fq[2] = s8 * s8; fq[3] = d8 * d8;
        const int woff = ((rt * 16 + lg * 4) * 2) ^ swz;   // b64, 8B-aligned
        #pragma unroll
        for (int q = 0; q < 4; ++q) {
            f32x4 dd = __builtin_amdgcn_mfma_f32_16x16x32_f16(fq[q], Bw, z, 0, 0, 0);
            *(f16x4*)((char*)&hT[wave][q][ln][0] + woff) =
                f16x4{(_Float16)dd[0], (_Float16)dd[1], (_Float16)dd[2], (_Float16)dd[3]};
        }
    }

    // ---- Phase 3: vertical conv via MFMA (weights as A) + SSIM.
    float lsum = 0.f;
    const float C1 = 1e-4f, C2 = 9e-4f;
    #pragma unroll
    for (int v = 0; v < 2; ++v) {
        const int roff = ((v * 16 + lg * 8) * 2) ^ swz;    // b128, 16B-aligned
        f32x4 accq[4];
        #pragma unroll
        for (int q = 0; q < 4; ++q) {
            f16x8 b = *(const f16x8*)((char*)&hT[wave][q][ln][0] + roff);
            accq[q] = __builtin_amdgcn_mfma_f32_16x16x32_f16(A2w, b, z, 0, 0, 0);
        }
        #pragma unroll
        for (int r = 0; r < 4; ++r) {
            float F1 = accq[0][r], F2 = accq[1][r];
            float F3 = accq[2][r], F4 = accq[3][r];
            float a = F1 * F1, bb = F2 * F2;
            float mpmt2 = 0.5f * (a - bb);           // 2*mp*mt
            float msq   = 0.5f * (a + bb);           // mp^2 + mt^2
            float cpt2  = 0.5f * (F3 - F4) - mpmt2;  // 2*sigma_pt
            float vsum  = 0.5f * (F3 + F4) - msq;    // sigma_p^2 + sigma_t^2
            float num = (mpmt2 + C1) * (cpt2 + C2);
            float den = (msq + C1) * (vsum + C2);
            lsum = fmaf(num, __builtin_amdgcn_rcpf(den), lsum);
        }
    }

    // ---- Short reduction tail: 2 shfl steps -> 16 partials/wave (mode 0).
    lsum += __shfl_down(lsum, 32, 64);
    lsum += __shfl_down(lsum, 16, 64);
    if (mode == 0) {
        if (lane < 16) partial[(nb * 4 + wave) * 16 + lane] = lsum;
    } else {
        lsum += __shfl_down(lsum, 8, 64);
        lsum += __shfl_down(lsum, 4, 64);
        lsum += __shfl_down(lsum, 2, 64);
        lsum += __shfl_down(lsum, 1, 64);
        if (lane == 0)
            atomicAdd(&acc[(nb * 4 + wave) & (NSLOT - 1)], (double)lsum);
    }
}

__global__ void ssim_init(double* acc)
{
    if (threadIdx.x < NSLOT) acc[threadIdx.x] = 0.0;
}

__global__ __launch_bounds__(1024)
void ssim_fin_slots(const float* __restrict__ partial, float* __restrict__ out,
                    int n4, double inv_n)
{
    __shared__ double red[16];
    double s = 0.0;
    const int tid = threadIdx.x;
    for (int i = tid; i < n4; i += 1024) {
        float4 v = ((const float4*)partial)[i];
        s += (double)v.x + (double)v.y + (double)v.z + (double)v.w;
    }
    #pragma unroll
    for (int off = 32; off > 0; off >>= 1)
        s += __shfl_down(s, off, 64);
    if ((tid & 63) == 0) red[tid >> 6] = s;
    __syncthreads();
    if (tid == 0) {
        double tot = 0.0;
        #pragma unroll
        for (int w = 0; w < 16; ++w) tot += red[w];
        out[0] = (float)(1.0 - tot * inv_n);
    }
}

__global__ void ssim_fin_atomic(const double* __restrict__ acc, float* __restrict__ out,
                                double inv_n)
{
    if (threadIdx.x == 0) {
        double s = 0.0;
        for (int i = 0; i < NSLOT; ++i) s += acc[i];
        out[0] = (float)(1.0 - s * inv_n);
    }
}

extern "C" void kernel_launch(void* const* d_in, const int* in_sizes, int n_in,
                              void* d_out, int out_size, void* d_ws, size_t ws_size,
                              hipStream_t stream)
{
    const float* pred = (const float*)d_in[0];
    const float* targ = (const float*)d_in[1];
    float* out = (float*)d_out;

    const long long total = (long long)in_sizes[0];       // 16*3*512*512
    const int n_img = (int)(total / (IMG_H * IMG_W));     // 48 planes
    dim3 grid(IMG_W / 64, IMG_H / 32, n_img);             // 8 x 16 x 48 = 6144
    const int nblk = grid.x * grid.y * grid.z;
    const int nslots = nblk * 64;                         // 16 floats per wave
    const double inv_n = 1.0 / (double)total;

    if (ws_size >= (size_t)nslots * sizeof(float)) {
        float* partial = (float*)d_ws;
        hipLaunchKernelGGL(ssim_main, grid, dim3(256), 0, stream,
                           pred, targ, partial, (double*)nullptr, 0);
        hipLaunchKernelGGL(ssim_fin_slots, dim3(1), dim3(1024), 0, stream,
                           partial, out, nslots / 4, inv_n);
    } else {
        double* acc = (double*)d_ws;
        hipLaunchKernelGGL(ssim_init, dim3(1), dim3(64), 0, stream, acc);
        hipLaunchKernelGGL(ssim_main, grid, dim3(256), 0, stream,
                           pred, targ, (float*)nullptr, acc, 1);
        hipLaunchKernelGGL(ssim_fin_atomic, dim3(1), dim3(1), 0, stream,
                           acc, out, inv_n);
    }
}

// Round 7
// 128.187 us; speedup vs baseline: 1.2371x; 1.2371x over previous
//
#include <hip/hip_runtime.h>
#include <math.h>

#define IMG_H 512
#define IMG_W 512
#define NSLOT 64

typedef _Float16 f16x2 __attribute__((ext_vector_type(2)));
typedef _Float16 f16x4 __attribute__((ext_vector_type(4)));
typedef _Float16 f16x8 __attribute__((ext_vector_type(8)));
typedef float    f32x4 __attribute__((ext_vector_type(4)));
typedef unsigned int uint;

// Zero-padded 11-tap Gaussian (sigma=1.5), f16, normalized (1/sum = 0.26601173).
// Index domain: idx in [-18, 33] -> WPAD[idx + 18]. Nonzero only for idx in [0,10].
__device__ const _Float16 WPAD[52] = {
    (_Float16)0.f,(_Float16)0.f,(_Float16)0.f,(_Float16)0.f,(_Float16)0.f,(_Float16)0.f,
    (_Float16)0.f,(_Float16)0.f,(_Float16)0.f,(_Float16)0.f,(_Float16)0.f,(_Float16)0.f,
    (_Float16)0.f,(_Float16)0.f,(_Float16)0.f,(_Float16)0.f,(_Float16)0.f,(_Float16)0.f,   // idx -18..-1
    (_Float16)0.00102838f, (_Float16)0.00759876f, (_Float16)0.03600077f,
    (_Float16)0.10936065f, (_Float16)0.21300554f, (_Float16)0.26601173f,
    (_Float16)0.21300554f, (_Float16)0.10936065f, (_Float16)0.03600077f,
    (_Float16)0.00759876f, (_Float16)0.00102838f,                                          // idx 0..10
    (_Float16)0.f,(_Float16)0.f,(_Float16)0.f,(_Float16)0.f,(_Float16)0.f,(_Float16)0.f,
    (_Float16)0.f,(_Float16)0.f,(_Float16)0.f,(_Float16)0.f,(_Float16)0.f,(_Float16)0.f,
    (_Float16)0.f,(_Float16)0.f,(_Float16)0.f,(_Float16)0.f,(_Float16)0.f,(_Float16)0.f,
    (_Float16)0.f,(_Float16)0.f,(_Float16)0.f,(_Float16)0.f,(_Float16)0.f                  // idx 11..33
};

__device__ __forceinline__ f16x8 frag_from_tab(int base)
{
    f16x8 f;
    #pragma unroll
    for (int j = 0; j < 8; ++j) f[j] = WPAD[base + j];
    return f;
}

// Wave-private everything; no block barriers, no manual fences. Coalesced
// global loads (lane = row-octet x 16B slice) + LDS transpose to A-fragments.
// LDS = 32768 B exactly -> 5 blocks/CU.
__global__ __launch_bounds__(256, 5)
void ssim_main(const float* __restrict__ pred, const float* __restrict__ targ,
               float* __restrict__ partial, double* __restrict__ acc, int mode)
{
    // Staging: [wave][{s,d}][16 rows][64 B pitch] — reused across 3 row-tiles.
    // Pitch 64 B: 2-way bank aliasing on stg ops, accepted for the occupancy.
    __shared__ __align__(128) _Float16 stg[4][2][16][32];      // 8192 B
    // Transpose buffer: [wave][q][out_col][halo_row 0..47], 16-byte XOR swizzle.
    __shared__ __align__(128) _Float16 hT[4][4][16][48];       // 24576 B

    const int tid  = threadIdx.x;
    const int lane = tid & 63, wave = tid >> 6;
    const int ln   = lane & 15, lg = lane >> 4;
    const int l8   = lane >> 3, l7 = lane & 7;

    // XCD swizzle: contiguous chunk (= whole planes) per XCD.
    const int bid   = ((blockIdx.z * 16 + blockIdx.y) * 8) + blockIdx.x;
    const int chunk = (int)gridDim.z << 4;            // nwg/8
    const int nb    = (bid & 7) * chunk + (bid >> 3);
    const int img   = nb >> 7;                        // 128 blocks per plane
    const int rem   = nb & 127;
    const int ty    = rem >> 3, tx = rem & 7;

    const float* __restrict__ p = pred + (size_t)img * (IMG_H * IMG_W);
    const float* __restrict__ t = targ + (size_t)img * (IMG_H * IMG_W);

    // Wave strip: output rows ty*32..+31, cols tx*64 + wave*16 ..+15.
    const int gr0 = ty * 32 - 5;                      // halo row 0 (48 rows)
    const int wo  = tx * 64 + wave * 16 - 8;          // halo col 0 (32 cols)

    // Banded Gaussian fragments:
    // Bw (B-op, horiz):  B[k][n] = w[k-n-3] -> WPAD[15 + lg*8+j - ln]
    // A2w (A-op, vert):  A[m][k] = w[k-m]   -> WPAD[18 + lg*8+j - ln]
    const f16x8 Bw  = frag_from_tab(15 + lg * 8 - ln);
    const f16x8 A2w = frag_from_tab(18 + lg * 8 - ln);
    const f32x4 z = {0.f, 0.f, 0.f, 0.f};

    // ---- Phase 1: coalesced loads. Lane l -> row (i*8 + l>>3), 16 B at (l&7)*16.
    const int  cb    = wo * 4 + l7 * 16;              // column byte offset in row
    const int  cbc   = cb < 0 ? 0 : (cb > 2032 ? 2032 : cb);
    const bool colOK = (cb == cbc);

    uint2 sp[6], dp[6];
    #pragma unroll
    for (int i = 0; i < 6; ++i) {
        const int gr  = gr0 + i * 8 + l8;
        const int grc = gr < 0 ? 0 : (gr > IMG_H - 1 ? IMG_H - 1 : gr);
        const char* rp = (const char*)p + (size_t)grc * (IMG_W * 4) + cbc;
        const char* rq = (const char*)t + (size_t)grc * (IMG_W * 4) + cbc;
        float4 pv = *(const float4*)rp;
        float4 tv = *(const float4*)rq;
        const bool ok = ((unsigned)gr < (unsigned)IMG_H) && colOK;
        f16x2 s01 = {(_Float16)(pv.x + tv.x), (_Float16)(pv.y + tv.y)};
        f16x2 s23 = {(_Float16)(pv.z + tv.z), (_Float16)(pv.w + tv.w)};
        f16x2 d01 = {(_Float16)(pv.x - tv.x), (_Float16)(pv.y - tv.y)};
        f16x2 d23 = {(_Float16)(pv.z - tv.z), (_Float16)(pv.w - tv.w)};
        uint2 sv = {__builtin_bit_cast(uint, s01), __builtin_bit_cast(uint, s23)};
        uint2 dv = {__builtin_bit_cast(uint, d01), __builtin_bit_cast(uint, d23)};
        const uint2 zz = {0u, 0u};
        sp[i] = ok ? sv : zz;
        dp[i] = ok ? dv : zz;
    }

    // ---- Phase 2: per row-tile: stage s,d -> read A-frags -> MFMA -> hT.
    // All LDS via plain C++: compiler orders may-alias DS ops (per-wave DS is
    // in-order) and inserts minimal lgkmcnt — no manual fences.
    char* stgS = (char*)&stg[wave][0][0][0];
    char* stgD = (char*)&stg[wave][1][0][0];
    const int wB  = l8 * 64 + l7 * 8;      // write byte (row l8, 8B col slot)
    const int rB  = ln * 64 + lg * 16;     // frag read byte (row ln, 16B slice)
    const int swz = (ln & 4) << 2;         // hT 16-byte XOR swizzle (write & read)

    #pragma unroll
    for (int rt = 0; rt < 3; ++rt) {
        *(uint2*)(stgS + wB)       = sp[2 * rt];
        *(uint2*)(stgS + wB + 512) = sp[2 * rt + 1];   // rows 8..15 (+8*64 B)
        *(uint2*)(stgD + wB)       = dp[2 * rt];
        *(uint2*)(stgD + wB + 512) = dp[2 * rt + 1];
        f16x8 s8 = *(const f16x8*)(stgS + rB);
        f16x8 d8 = *(const f16x8*)(stgD + rB);
        f16x8 fq[4];
        fq[0] = s8; fq[1] = d8;
        fq[2] = s8 * s8; fq[3] = d8 * d8;
        const int woff = ((rt * 16 + lg * 4) * 2) ^ swz;   // b64, 8B-aligned
        #pragma unroll
        for (int q = 0; q < 4; ++q) {
            f32x4 dd = __builtin_amdgcn_mfma_f32_16x16x32_f16(fq[q], Bw, z, 0, 0, 0);
            *(f16x4*)((char*)&hT[wave][q][ln][0] + woff) =
                f16x4{(_Float16)dd[0], (_Float16)dd[1], (_Float16)dd[2], (_Float16)dd[3]};
        }
    }

    // ---- Phase 3: vertical conv via MFMA (weights as A) + SSIM.
    float lsum = 0.f;
    const float C1 = 1e-4f, C2 = 9e-4f;
    #pragma unroll
    for (int v = 0; v < 2; ++v) {
        const int roff = ((v * 16 + lg * 8) * 2) ^ swz;    // b128, 16B-aligned
        f32x4 accq[4];
        #pragma unroll
        for (int q = 0; q < 4; ++q) {
            f16x8 b = *(const f16x8*)((char*)&hT[wave][q][ln][0] + roff);
            accq[q] = __builtin_amdgcn_mfma_f32_16x16x32_f16(A2w, b, z, 0, 0, 0);
        }
        #pragma unroll
        for (int r = 0; r < 4; ++r) {
            float F1 = accq[0][r], F2 = accq[1][r];
            float F3 = accq[2][r], F4 = accq[3][r];
            float a = F1 * F1, bb = F2 * F2;
            float mpmt2 = 0.5f * (a - bb);           // 2*mp*mt
            float msq   = 0.5f * (a + bb);           // mp^2 + mt^2
            float cpt2  = 0.5f * (F3 - F4) - mpmt2;  // 2*sigma_pt
            float vsum  = 0.5f * (F3 + F4) - msq;    // sigma_p^2 + sigma_t^2
            float num = (mpmt2 + C1) * (cpt2 + C2);
            float den = (msq + C1) * (vsum + C2);
            lsum = fmaf(num, __builtin_amdgcn_rcpf(den), lsum);
        }
    }

    // ---- Wave reduce -> per-wave slot (mode 0) or atomic (mode 1).
    // Full shfl chain: hidden by other resident waves; keeps partials small
    // (96 KB) so the single-block finalizer stays ~3-5 us (round-6 lesson).
    #pragma unroll
    for (int off = 32; off > 0; off >>= 1)
        lsum += __shfl_down(lsum, off, 64);
    if (lane == 0) {
        if (mode == 0) partial[nb * 4 + wave] = lsum;
        else atomicAdd(&acc[(nb * 4 + wave) & (NSLOT - 1)], (double)lsum);
    }
}

__global__ void ssim_init(double* acc)
{
    if (threadIdx.x < NSLOT) acc[threadIdx.x] = 0.0;
}

__global__ __launch_bounds__(1024)
void ssim_fin_slots(const float* __restrict__ partial, float* __restrict__ out,
                    int n4, double inv_n)
{
    __shared__ double red[16];
    double s = 0.0;
    const int tid = threadIdx.x;
    for (int i = tid; i < n4; i += 1024) {
        float4 v = ((const float4*)partial)[i];
        s += (double)v.x + (double)v.y + (double)v.z + (double)v.w;
    }
    #pragma unroll
    for (int off = 32; off > 0; off >>= 1)
        s += __shfl_down(s, off, 64);
    if ((tid & 63) == 0) red[tid >> 6] = s;
    __syncthreads();
    if (tid == 0) {
        double tot = 0.0;
        #pragma unroll
        for (int w = 0; w < 16; ++w) tot += red[w];
        out[0] = (float)(1.0 - tot * inv_n);
    }
}

__global__ void ssim_fin_atomic(const double* __restrict__ acc, float* __restrict__ out,
                                double inv_n)
{
    if (threadIdx.x == 0) {
        double s = 0.0;
        for (int i = 0; i < NSLOT; ++i) s += acc[i];
        out[0] = (float)(1.0 - s * inv_n);
    }
}

extern "C" void kernel_launch(void* const* d_in, const int* in_sizes, int n_in,
                              void* d_out, int out_size, void* d_ws, size_t ws_size,
                              hipStream_t stream)
{
    const float* pred = (const float*)d_in[0];
    const float* targ = (const float*)d_in[1];
    float* out = (float*)d_out;

    const long long total = (long long)in_sizes[0];       // 16*3*512*512
    const int n_img = (int)(total / (IMG_H * IMG_W));     // 48 planes
    dim3 grid(IMG_W / 64, IMG_H / 32, n_img);             // 8 x 16 x 48 = 6144
    const int nblk = grid.x * grid.y * grid.z;
    const int nslots = nblk * 4;
    const double inv_n = 1.0 / (double)total;

    if (ws_size >= (size_t)nslots * sizeof(float)) {
        float* partial = (float*)d_ws;
        hipLaunchKernelGGL(ssim_main, grid, dim3(256), 0, stream,
                           pred, targ, partial, (double*)nullptr, 0);
        hipLaunchKernelGGL(ssim_fin_slots, dim3(1), dim3(1024), 0, stream,
                           partial, out, nslots / 4, inv_n);
    } else {
        double* acc = (double*)d_ws;
        hipLaunchKernelGGL(ssim_init, dim3(1), dim3(64), 0, stream, acc);
        hipLaunchKernelGGL(ssim_main, grid, dim3(256), 0, stream,
                           pred, targ, (float*)nullptr, acc, 1);
        hipLaunchKernelGGL(ssim_fin_atomic, dim3(1), dim3(1), 0, stream,
                           acc, out, inv_n);
    }
}